// Round 15
// baseline (98.211 us; speedup 1.0000x reference)
//
#include <hip/hip_runtime.h>
#include <hip/hip_bf16.h>

// Problem constants (from reference)
#define BB   16
#define NS   1024
#define NT   4096
#define CIN  256
#define CSK  64
#define HD   256           // hidden dim / output cols
#define K1   (CIN + CSK)   // 320
#define MTOT (BB * NT)     // 65536

typedef __attribute__((ext_vector_type(4))) float f32x4;
typedef __attribute__((ext_vector_type(8))) __bf16 bf16x8;
typedef __attribute__((ext_vector_type(4))) unsigned short ushort4v;

// ws layout (bytes)
#define W1F_OFF 0u                    // bf16[320*256]    = 163840
#define W2F_OFF 163840u               // bf16[256*256]    = 131072

static __device__ __forceinline__ unsigned short f2bf(float f) {
    union { float f; unsigned int u; } v; v.f = f;
    unsigned int r = (v.u + 0x7FFFu + ((v.u >> 16) & 1u)) >> 16;
    return (unsigned short)r;
}
// HW bf16 convert (RNE — bit-identical to f2bf on finite)
static __device__ __forceinline__ unsigned short f2bf_hw(float f) {
    union { __bf16 b; unsigned short u; } v; v.b = (__bf16)f;
    return v.u;
}

// ---- prep: W1/W2 swizzle into MFMA B-fragment order + out tail section ----
// Wf layout: Wf[kblk][n(16)][lane(64)][8]
//   k = kblk*32 + (lane>>4)*8 + j ; col = n*16 + (lane&15)
#define PREP_B1 (K1 * HD / 256)         // 320 blocks for W1f
#define PREP_B2 (HD * HD / 256)         // 256 blocks for W2f
#define PREP_B3 ((MTOT * 3) / 256)      // 768 blocks for tail
__global__ __launch_bounds__(256) void prep_kernel(
    const float* __restrict__ W1, const float* __restrict__ W2,
    const float* __restrict__ pos_skip,
    unsigned short* __restrict__ W1f, unsigned short* __restrict__ W2f,
    float* __restrict__ out)
{
    const int b = blockIdx.x;
    if (b < PREP_B1 + PREP_B2) {
        const bool is1 = b < PREP_B1;
        const int id = (is1 ? b : b - PREP_B1) * 256 + threadIdx.x;
        const int j    = id & 7;
        const int lane = (id >> 3) & 63;
        const int n    = (id >> 9) & 15;
        const int kblk = id >> 13;
        const int k   = kblk * 32 + (lane >> 4) * 8 + j;
        const int col = n * 16 + (lane & 15);
        if (is1) W1f[id] = f2bf(W1[(size_t)k * HD + col]);
        else     W2f[id] = f2bf(W2[(size_t)k * HD + col]);
    } else {
        const int i = (b - PREP_B1 - PREP_B2) * 256 + threadIdx.x;
        const size_t o1 = (size_t)MTOT * HD;
        out[o1 + i] = pos_skip[i];                                  // i < MTOT*3
        if (i < MTOT) out[o1 + (size_t)MTOT * 3 + i] = (float)(i >> 12);
    }
}

// ===== PIPELINED MEGAKERNEL: 2 row-groups per block =====
// 512 blocks, each owns groups {2t, 2t+1} of one cloud (cloud<->XCD affine).
// sp (16 KB) persists; ldsA (40 KB) per-group A/h1 tile. LDS 56 KB -> 2/CU.
// Group g+1's kNN candidate loop (f64-key, r13-proven) is interleaved into
// group g's GEMM k-loops: MFMA pipe runs under kNN VALU. Exposed kNN: only
// group 0's. Barriers: 8 total.
__global__ __launch_bounds__(256, 2) void fp_fused_kernel(
    const float* __restrict__ x, const float* __restrict__ x_skip,
    const float* __restrict__ pos, const float* __restrict__ pos_skip,
    const unsigned short* __restrict__ W1f, const unsigned short* __restrict__ W2f,
    const float* __restrict__ b1, const float* __restrict__ b2,
    float* __restrict__ out)
{
    __shared__ float4 sp[NS];                                   // 16 KB persistent
    __shared__ __align__(16) unsigned short ldsA[10 * 4 * 512]; // 40 KB

    const int tid = threadIdx.x;
    const int w = tid >> 6, lane = tid & 63;
    const int l15 = lane & 15, lk = lane >> 4;
    const int p    = tid & 3;       // kNN partition
    const int qloc = tid >> 2;      // kNN query within group

    // cloud<->XCD affinity (bijective on [0,512))
    const int bid   = blockIdx.x;
    const int xcd   = bid & 7;
    const int j     = bid >> 3;                 // 0..63
    const int cloud = xcd + 8 * (j >> 5);       // 0..15
    const int j2    = j & 31;                   // 0..31
    const int bm0   = cloud * 64 + j2 * 2;      // group-0 64-row block
    const int bm1   = bm0 + 1;

    const unsigned short* w1p = W1f + (w * 4) * 512 + lane * 8;
    const unsigned short* w2p = W2f + (w * 4) * 512 + lane * 8;

    // ---- stage sp once (persistent for both groups) ----
    {
        const float* pc = pos + (size_t)cloud * NS * 3;
        for (int i = tid; i < NS; i += 256)
            sp[i] = make_float4(pc[i * 3 + 0], pc[i * 3 + 1], pc[i * 3 + 2], 0.f);
    }
    __syncthreads();                                            // [1]

    // ---- kNN machinery (r13 f64 lex-key, exact) ----
    double kb0_, kb1_, kb2_, ksi_;
    float  kqx, kqy, kqz;
    int    myi0, myi1, myi2;
    float  myw0, myw1, myw2;

    auto knn_init = [&](int bm) {
        const int rg = bm * 64 + qloc;
        kqx = pos_skip[rg * 3 + 0];
        kqy = pos_skip[rg * 3 + 1];
        kqz = pos_skip[rg * 3 + 2];
        kb0_ = 1e300; kb1_ = 1e300; kb2_ = 1e300;
        ksi_ = (double)p;
    };
    // per-lane candidate iterations [start, start+cnt) of 256 total
    auto knn_chunk = [&](int start, int cnt) {
        #pragma unroll 4
        for (int t = 0; t < cnt; ++t) {
            const int s = (start + t) * 4 + p;
            float4 c = sp[s];
            float dx = kqx - c.x, dy = kqy - c.y, dz = kqz - c.z;
            float d = dx * dx + dy * dy + dz * dz;
            double key = fma((double)__float_as_uint(d), 1024.0, ksi_);
            ksi_ += 4.0;
            double nb0 = fmin(kb0_, key);
            double nb1 = fmax(kb0_, fmin(kb1_, key));
            double nb2 = fmax(kb1_, fmin(kb2_, key));
            kb0_ = nb0; kb1_ = nb1; kb2_ = nb2;
        }
    };
    auto knn_finish = [&]() {
        #pragma unroll
        for (int m = 1; m <= 2; m <<= 1) {
            double o0 = __shfl_xor(kb0_, m, 64);
            double o1 = __shfl_xor(kb1_, m, 64);
            double o2 = __shfl_xor(kb2_, m, 64);
            double nb0, nb1, nb2;
            nb0 = fmin(kb0_, o0); nb1 = fmax(kb0_, fmin(kb1_, o0)); nb2 = fmax(kb1_, fmin(kb2_, o0));
            kb0_ = nb0; kb1_ = nb1; kb2_ = nb2;
            nb0 = fmin(kb0_, o1); nb1 = fmax(kb0_, fmin(kb1_, o1)); nb2 = fmax(kb1_, fmin(kb2_, o1));
            kb0_ = nb0; kb1_ = nb1; kb2_ = nb2;
            nb0 = fmin(kb0_, o2); nb1 = fmax(kb0_, fmin(kb1_, o2)); nb2 = fmax(kb1_, fmin(kb2_, o2));
            kb0_ = nb0; kb1_ = nb1; kb2_ = nb2;
        }
        unsigned long long k0 = (unsigned long long)kb0_;
        unsigned long long k1 = (unsigned long long)kb1_;
        unsigned long long k2 = (unsigned long long)kb2_;
        myi0 = (int)(k0 & 1023ull);
        myi1 = (int)(k1 & 1023ull);
        myi2 = (int)(k2 & 1023ull);
        float d0 = __uint_as_float((unsigned int)(k0 >> 10));
        float d1 = __uint_as_float((unsigned int)(k1 >> 10));
        float d2 = __uint_as_float((unsigned int)(k2 >> 10));
        float w0 = 1.f / fmaxf(d0, 1e-16f);
        float w1 = 1.f / fmaxf(d1, 1e-16f);
        float w2 = 1.f / fmaxf(d2, 1e-16f);
        float inv = 1.f / (w0 + w1 + w2);
        myw0 = w0 * inv; myw1 = w1 * inv; myw2 = w2 * inv;
    };

    // ---- one-shot A gather/blend (all 320 cols -> ldsA), r13-proven ----
    auto gather = [&](int bm) {
        const int cb  = cloud * NS;
        const int kbm = lane >> 3;              // main: c=4*lane -> kb (0..7)
        const int lkm = (lane >> 1) & 3;
        const int em  = lane & 1;
        const int kbs = 8 + (lane >> 5);        // skip: c=256+lane -> kb (8,9)
        const int lks = (lane >> 3) & 3;
        const int jjs = lane & 7;
        #pragma unroll
        for (int r16 = 0; r16 < 16; ++r16) {
            const int src = r16 * 4;
            const int i0 = cb + __shfl(myi0, src, 64);
            const int i1 = cb + __shfl(myi1, src, 64);
            const int i2 = cb + __shfl(myi2, src, 64);
            const float w0 = __shfl(myw0, src, 64);
            const float w1 = __shfl(myw1, src, 64);
            const float w2 = __shfl(myw2, src, 64);
            const int row = w * 16 + r16;
            const int rg  = bm * 64 + row;
            f32x4 a = *(const f32x4*)(x + (size_t)i0 * CIN + lane * 4);
            f32x4 b = *(const f32x4*)(x + (size_t)i1 * CIN + lane * 4);
            f32x4 c = *(const f32x4*)(x + (size_t)i2 * CIN + lane * 4);
            float s = x_skip[(size_t)rg * CSK + lane];
            f32x4 r = a * w0 + b * w1 + c * w2;
            int H = ((kbm * 4 + w) * 64 + (r16 + 16 * lkm)) * 8 + 4 * em;
            H ^= (kbm & 7) << 3;
            ushort4v o4 = { f2bf_hw(r[0]), f2bf_hw(r[1]), f2bf_hw(r[2]), f2bf_hw(r[3]) };
            *(ushort4v*)&ldsA[H] = o4;
            int H2 = ((kbs * 4 + w) * 64 + (r16 + 16 * lks)) * 8 + jjs;
            H2 ^= (kbs & 7) << 3;
            ldsA[H2] = f2bf_hw(s);
        }
    };

    // ---- GEMM1 + h1 repack + GEMM2 + store for one group; optionally
    //      interleave next group's kNN chunks (16/kb GEMM1, 12/kb GEMM2) ----
    auto run_group = [&](int bm, bool doknn) {
        f32x4 acc[4][4];
        #pragma unroll
        for (int mf = 0; mf < 4; ++mf)
            #pragma unroll
            for (int nf = 0; nf < 4; ++nf)
                acc[mf][nf] = f32x4{0.f, 0.f, 0.f, 0.f};
        {
            bf16x8 bc[4], bn[4];
            #pragma unroll
            for (int nf = 0; nf < 4; ++nf)
                bc[nf] = *(const bf16x8*)(w1p + nf * 512);
            for (int kb = 0; kb < 10; ++kb) {
                if (kb < 9) {
                    #pragma unroll
                    for (int nf = 0; nf < 4; ++nf)
                        bn[nf] = *(const bf16x8*)(w1p + (size_t)(kb + 1) * 8192 + nf * 512);
                }
                bf16x8 a[4];
                #pragma unroll
                for (int mf = 0; mf < 4; ++mf) {
                    int aoff = ((kb * 4 + mf) * 64 + lane) * 8;
                    aoff ^= (kb & 7) << 3;
                    a[mf] = *(const bf16x8*)&ldsA[aoff];
                }
                #pragma unroll
                for (int mf = 0; mf < 4; ++mf)
                    #pragma unroll
                    for (int nf = 0; nf < 4; ++nf)
                        acc[mf][nf] = __builtin_amdgcn_mfma_f32_16x16x32_bf16(
                            a[mf], bc[nf], acc[mf][nf], 0, 0, 0);
                if (doknn) knn_chunk(kb * 16, 16);       // 160 candidates here
                #pragma unroll
                for (int nf = 0; nf < 4; ++nf) bc[nf] = bn[nf];
            }
        }
        __syncthreads();   // ldsA reads done; safe to overwrite with h1

        // h1 = relu(acc + b1) -> bf16 -> ldsA in A-frag layout
        #pragma unroll
        for (int nf = 0; nf < 4; ++nf) {
            const int col = w * 64 + nf * 16 + l15;
            const float bv = b1[col];
            const int kb2   = 2 * w + (nf >> 1);
            const int lane2 = lk * 4 + 16 * ((nf & 1) * 2 + (l15 >> 3));
            #pragma unroll
            for (int mf = 0; mf < 4; ++mf) {
                #pragma unroll
                for (int r = 0; r < 4; ++r) {
                    float v = fmaxf(acc[mf][nf][r] + bv, 0.f);
                    ldsA[((kb2 * 4 + mf) * 64 + lane2 + r) * 8 + (l15 & 7)] = f2bf_hw(v);
                }
            }
        }
        __syncthreads();   // h1 tile complete

        f32x4 acc2[4][4];
        #pragma unroll
        for (int mf = 0; mf < 4; ++mf)
            #pragma unroll
            for (int nf = 0; nf < 4; ++nf)
                acc2[mf][nf] = f32x4{0.f, 0.f, 0.f, 0.f};
        {
            bf16x8 bc[4], bn[4];
            #pragma unroll
            for (int nf = 0; nf < 4; ++nf)
                bc[nf] = *(const bf16x8*)(w2p + nf * 512);
            for (int kb = 0; kb < 8; ++kb) {
                if (kb < 7) {
                    #pragma unroll
                    for (int nf = 0; nf < 4; ++nf)
                        bn[nf] = *(const bf16x8*)(w2p + (size_t)(kb + 1) * 8192 + nf * 512);
                }
                bf16x8 a[4];
                #pragma unroll
                for (int mf = 0; mf < 4; ++mf)
                    a[mf] = *(const bf16x8*)&ldsA[((kb * 4 + mf) * 64 + lane) * 8];
                #pragma unroll
                for (int mf = 0; mf < 4; ++mf)
                    #pragma unroll
                    for (int nf = 0; nf < 4; ++nf)
                        acc2[mf][nf] = __builtin_amdgcn_mfma_f32_16x16x32_bf16(
                            a[mf], bc[nf], acc2[mf][nf], 0, 0, 0);
                if (doknn) knn_chunk(160 + kb * 12, 12); // remaining 96
                #pragma unroll
                for (int nf = 0; nf < 4; ++nf) bc[nf] = bn[nf];
            }
        }
        // epilogue: out = relu(acc2 + b2), f32
        const int rbase = bm * 64 + lk * 4;
        const int cbase = w * 64 + l15;
        #pragma unroll
        for (int nf = 0; nf < 4; ++nf) {
            const int col = cbase + nf * 16;
            const float bv = b2[col];
            #pragma unroll
            for (int mf = 0; mf < 4; ++mf) {
                #pragma unroll
                for (int r = 0; r < 4; ++r) {
                    float v = fmaxf(acc2[mf][nf][r] + bv, 0.f);
                    out[(size_t)(rbase + mf * 16 + r) * HD + col] = v;
                }
            }
        }
    };

    // ================= pipeline =================
    knn_init(bm0);
    knn_chunk(0, 256);          // group-0 kNN (exposed, once per block)
    knn_finish();
    gather(bm0);
    __syncthreads();            // [2] A(g0) ready

    knn_init(bm1);              // g1 state; chunks run inside run_group(g0)
    run_group(bm0, true);
    __syncthreads();            // [.] all ldsA(h1 g0) reads done

    knn_finish();               // g1 results
    gather(bm1);
    __syncthreads();            // [.] A(g1) ready

    run_group(bm1, false);
}

extern "C" void kernel_launch(void* const* d_in, const int* in_sizes, int n_in,
                              void* d_out, int out_size, void* d_ws, size_t ws_size,
                              hipStream_t stream)
{
    const float* x        = (const float*)d_in[0];
    const float* pos      = (const float*)d_in[1];
    const float* x_skip   = (const float*)d_in[2];
    const float* pos_skip = (const float*)d_in[3];
    const float* W1       = (const float*)d_in[4];
    const float* b1       = (const float*)d_in[5];
    const float* W2       = (const float*)d_in[6];
    const float* b2       = (const float*)d_in[7];
    float* out = (float*)d_out;

    char* ws = (char*)d_ws;
    unsigned short* W1f  = (unsigned short*)(ws + W1F_OFF);
    unsigned short* W2f  = (unsigned short*)(ws + W2F_OFF);

    prep_kernel<<<PREP_B1 + PREP_B2 + PREP_B3, 256, 0, stream>>>(
        W1, W2, pos_skip, W1f, W2f, out);
    fp_fused_kernel<<<MTOT / 128, 256, 0, stream>>>(
        x, x_skip, pos, pos_skip, W1f, W2f, b1, b2, out);
}

// Round 16
// 64.982 us; speedup vs baseline: 1.5114x; 1.5114x over previous
//
#include <hip/hip_runtime.h>
#include <hip/hip_bf16.h>

// Problem constants (from reference)
#define BB   16
#define NS   1024
#define NT   4096
#define CIN  256
#define CSK  64
#define HD   256           // hidden dim / output cols
#define K1   (CIN + CSK)   // 320
#define MTOT (BB * NT)     // 65536

typedef __attribute__((ext_vector_type(4))) float f32x4;
typedef __attribute__((ext_vector_type(8))) __bf16 bf16x8;
typedef __attribute__((ext_vector_type(4))) unsigned short ushort4v;

// ws layout (bytes)
#define W1F_OFF 0u                    // bf16[320*256]    = 163840
#define W2F_OFF 163840u               // bf16[256*256]    = 131072

static __device__ __forceinline__ unsigned short f2bf(float f) {
    union { float f; unsigned int u; } v; v.f = f;
    unsigned int r = (v.u + 0x7FFFu + ((v.u >> 16) & 1u)) >> 16;
    return (unsigned short)r;
}
// HW bf16 convert (RNE — bit-identical to f2bf on finite)
static __device__ __forceinline__ unsigned short f2bf_hw(float f) {
    union { __bf16 b; unsigned short u; } v; v.b = (__bf16)f;
    return v.u;
}

// ---- prep: W1/W2 swizzle into MFMA B-fragment order (tail moved to fused) ----
// Wf layout: Wf[kblk][n(16)][lane(64)][8]
//   k = kblk*32 + (lane>>4)*8 + j ; col = n*16 + (lane&15)
#define PREP_B1 (K1 * HD / 256)         // 320 blocks for W1f
#define PREP_B2 (HD * HD / 256)         // 256 blocks for W2f
__global__ __launch_bounds__(256) void prep_kernel(
    const float* __restrict__ W1, const float* __restrict__ W2,
    unsigned short* __restrict__ W1f, unsigned short* __restrict__ W2f)
{
    const int b = blockIdx.x;
    const bool is1 = b < PREP_B1;
    const int id = (is1 ? b : b - PREP_B1) * 256 + threadIdx.x;
    const int j    = id & 7;
    const int lane = (id >> 3) & 63;
    const int n    = (id >> 9) & 15;
    const int kblk = id >> 13;
    const int k   = kblk * 32 + (lane >> 4) * 8 + j;
    const int col = n * 16 + (lane & 15);
    if (is1) W1f[id] = f2bf(W1[(size_t)k * HD + col]);
    else     W2f[id] = f2bf(W2[(size_t)k * HD + col]);
}

// ===== MEGAKERNEL: kNN + interp-gather + GEMM1 + GEMM2 per 64-row block =====
// r13 structure (best: 62.9 µs). Barrier-minimal (5 barriers). B operands
// stream L2->VGPR (no ldsB). ldsA = exactly 40960 B -> 4 blocks/CU.
// kNN key: u64 (d_bits<<10 | s) reinterpreted as f64 DENORMAL — positive-f64
// compare == u64 bit compare, so fmin/fmax_f64 give exact (d,s)-lex order
// (same semantics as the passing f64-fma key, 6 fewer cycles per candidate;
// f64 denormals are IEEE on AMDGPU, never flushed).
__global__ __launch_bounds__(256, 4) void fp_fused_kernel(
    const float* __restrict__ x, const float* __restrict__ x_skip,
    const float* __restrict__ pos, const float* __restrict__ pos_skip,
    const unsigned short* __restrict__ W1f, const unsigned short* __restrict__ W2f,
    const float* __restrict__ b1, const float* __restrict__ b2,
    float* __restrict__ out)
{
    __shared__ __align__(16) unsigned short ldsA[10 * 4 * 512]; // 40 KB exactly

    const int tid = threadIdx.x;
    const int w = tid >> 6, lane = tid & 63;
    const int l15 = lane & 15, lk = lane >> 4;

    // cloud<->XCD affinity (bijective on [0,1024))
    const int bid   = blockIdx.x;
    const int xcd   = bid & 7;
    const int j     = bid >> 3;                 // 0..127
    const int cloud = xcd + 8 * (j >> 6);       // 0..15
    const int bm    = cloud * 64 + (j & 63);    // 64-row block index

    // B source pointers; prefetch GEMM1's first 4 B-frags before kNN
    const unsigned short* w1p = W1f + (w * 4) * 512 + lane * 8;
    const unsigned short* w2p = W2f + (w * 4) * 512 + lane * 8;
    bf16x8 bpre[4];
    #pragma unroll
    for (int nf = 0; nf < 4; ++nf)
        bpre[nf] = *(const bf16x8*)(w1p + nf * 512);

    // ---------------- phase 1: kNN for this block's 64 queries ----------------
    // Query q = tid>>2, partition p = tid&3.
    int   myi0, myi1, myi2;
    float myw0, myw1, myw2;
    {
        float4* sp = (float4*)ldsA;             // 16 KB overlay, dead after phase 1
        const float* pc = pos + (size_t)cloud * NS * 3;
        for (int i = tid; i < NS; i += 256)
            sp[i] = make_float4(pc[i * 3 + 0], pc[i * 3 + 1], pc[i * 3 + 2], 0.f);
        __syncthreads();                                            // [1]

        const int p  = tid & 3;
        const int rg = bm * 64 + (tid >> 2);
        const float qx = pos_skip[rg * 3 + 0];
        const float qy = pos_skip[rg * 3 + 1];
        const float qz = pos_skip[rg * 3 + 2];

        double b0 = 1e300, b1k = 1e300, b2k = 1e300;
        #pragma unroll 4
        for (int i = 0; i < NS / 4; ++i) {
            const int s = i * 4 + p;
            float4 c = sp[s];
            float dx = qx - c.x, dy = qy - c.y, dz = qz - c.z;
            float d = dx * dx + dy * dy + dz * dz;
            unsigned long long k64 =
                ((unsigned long long)__float_as_uint(d) << 10) | (unsigned long long)s;
            double key = __longlong_as_double((long long)k64); // positive denormal
            double nb0 = fmin(b0, key);
            double nb1 = fmax(b0, fmin(b1k, key));
            double nb2 = fmax(b1k, fmin(b2k, key));
            b0 = nb0; b1k = nb1; b2k = nb2;
        }
        #pragma unroll
        for (int m = 1; m <= 2; m <<= 1) {
            double o0 = __shfl_xor(b0, m, 64);
            double o1 = __shfl_xor(b1k, m, 64);
            double o2 = __shfl_xor(b2k, m, 64);
            double nb0, nb1, nb2;
            nb0 = fmin(b0, o0); nb1 = fmax(b0, fmin(b1k, o0)); nb2 = fmax(b1k, fmin(b2k, o0));
            b0 = nb0; b1k = nb1; b2k = nb2;
            nb0 = fmin(b0, o1); nb1 = fmax(b0, fmin(b1k, o1)); nb2 = fmax(b1k, fmin(b2k, o1));
            b0 = nb0; b1k = nb1; b2k = nb2;
            nb0 = fmin(b0, o2); nb1 = fmax(b0, fmin(b1k, o2)); nb2 = fmax(b1k, fmin(b2k, o2));
            b0 = nb0; b1k = nb1; b2k = nb2;
        }
        // all 4 lanes of the group hold the merged triple -> decode (reinterpret)
        unsigned long long k0 = (unsigned long long)__double_as_longlong(b0);
        unsigned long long k1 = (unsigned long long)__double_as_longlong(b1k);
        unsigned long long k2 = (unsigned long long)__double_as_longlong(b2k);
        myi0 = (int)(k0 & 1023ull);
        myi1 = (int)(k1 & 1023ull);
        myi2 = (int)(k2 & 1023ull);
        float d0 = __uint_as_float((unsigned int)(k0 >> 10));
        float d1 = __uint_as_float((unsigned int)(k1 >> 10));
        float d2 = __uint_as_float((unsigned int)(k2 >> 10));
        float w0 = 1.f / fmaxf(d0, 1e-16f);
        float w1 = 1.f / fmaxf(d1, 1e-16f);
        float w2 = 1.f / fmaxf(d2, 1e-16f);
        float inv = 1.f / (w0 + w1 + w2);
        myw0 = w0 * inv; myw1 = w1 * inv; myw2 = w2 * inv;
        __syncthreads();   // [2] sp reads complete (ldsA about to be overwritten)
    }

    // ------- phase 2: one-shot A gather/blend (all 320 cols -> ldsA) -------
    // Row w*16+r16's kNN result lives in lane 4*r16 of THIS wave.
    {
        const int cb  = cloud * NS;             // cloud base row in x
        const int kbm = lane >> 3;              // main: c=4*lane -> kb (0..7)
        const int lkm = (lane >> 1) & 3;
        const int em  = lane & 1;
        const int kbs = 8 + (lane >> 5);        // skip: c=256+lane -> kb (8,9)
        const int lks = (lane >> 3) & 3;
        const int jjs = lane & 7;
        #pragma unroll
        for (int r16 = 0; r16 < 16; ++r16) {
            const int src = r16 * 4;
            const int i0 = cb + __shfl(myi0, src, 64);
            const int i1 = cb + __shfl(myi1, src, 64);
            const int i2 = cb + __shfl(myi2, src, 64);
            const float w0 = __shfl(myw0, src, 64);
            const float w1 = __shfl(myw1, src, 64);
            const float w2 = __shfl(myw2, src, 64);
            const int row = w * 16 + r16;
            const int rg  = bm * 64 + row;
            f32x4 a = *(const f32x4*)(x + (size_t)i0 * CIN + lane * 4);
            f32x4 b = *(const f32x4*)(x + (size_t)i1 * CIN + lane * 4);
            f32x4 c = *(const f32x4*)(x + (size_t)i2 * CIN + lane * 4);
            float s = x_skip[(size_t)rg * CSK + lane];
            f32x4 r = a * w0 + b * w1 + c * w2;
            int H = ((kbm * 4 + w) * 64 + (r16 + 16 * lkm)) * 8 + 4 * em;
            H ^= (kbm & 7) << 3;
            ushort4v o4 = { f2bf_hw(r[0]), f2bf_hw(r[1]), f2bf_hw(r[2]), f2bf_hw(r[3]) };
            *(ushort4v*)&ldsA[H] = o4;
            int H2 = ((kbs * 4 + w) * 64 + (r16 + 16 * lks)) * 8 + jjs;
            H2 ^= (kbs & 7) << 3;
            ldsA[H2] = f2bf_hw(s);
        }
    }
    __syncthreads();   // [3] A tile complete

    // ---------------- phase 3: GEMM1 k-loop, barrier-free (B: L2->VGPR) ----------------
    f32x4 acc[4][4];
    #pragma unroll
    for (int mf = 0; mf < 4; ++mf)
        #pragma unroll
        for (int nf = 0; nf < 4; ++nf)
            acc[mf][nf] = f32x4{0.f, 0.f, 0.f, 0.f};

    {
        bf16x8 bc[4], bn[4];
        #pragma unroll
        for (int nf = 0; nf < 4; ++nf) bc[nf] = bpre[nf];
        #pragma unroll
        for (int kb = 0; kb < 10; ++kb) {
            if (kb < 9) {
                #pragma unroll
                for (int nf = 0; nf < 4; ++nf)
                    bn[nf] = *(const bf16x8*)(w1p + (size_t)(kb + 1) * 8192 + nf * 512);
            }
            bf16x8 a[4];
            #pragma unroll
            for (int mf = 0; mf < 4; ++mf) {
                int aoff = ((kb * 4 + mf) * 64 + lane) * 8;
                aoff ^= (kb & 7) << 3;
                a[mf] = *(const bf16x8*)&ldsA[aoff];
            }
            #pragma unroll
            for (int mf = 0; mf < 4; ++mf)
                #pragma unroll
                for (int nf = 0; nf < 4; ++nf)
                    acc[mf][nf] = __builtin_amdgcn_mfma_f32_16x16x32_bf16(
                        a[mf], bc[nf], acc[mf][nf], 0, 0, 0);
            #pragma unroll
            for (int nf = 0; nf < 4; ++nf) bc[nf] = bn[nf];
        }
    }
    __syncthreads();   // [4] all ldsA reads done; safe to overwrite with h1

    // ------- phase 4: h1 = relu(acc + b1) -> bf16 -> ldsA in A-frag layout -------
    // elem (row=mf*16+lk*4+r, col=w*64+nf*16+l15):
    //   kb2 = 2w + (nf>>1); lane2 = lk*4+r + 16*((nf&1)*2 + (l15>>3)); j = l15&7
    #pragma unroll
    for (int nf = 0; nf < 4; ++nf) {
        const int col = w * 64 + nf * 16 + l15;
        const float bv = b1[col];
        const int kb2   = 2 * w + (nf >> 1);
        const int lane2 = lk * 4 + 16 * ((nf & 1) * 2 + (l15 >> 3));
        #pragma unroll
        for (int mf = 0; mf < 4; ++mf) {
            #pragma unroll
            for (int r = 0; r < 4; ++r) {
                float v = fmaxf(acc[mf][nf][r] + bv, 0.f);
                ldsA[((kb2 * 4 + mf) * 64 + lane2 + r) * 8 + (l15 & 7)] = f2bf_hw(v);
            }
        }
    }
    __syncthreads();   // [5] h1 tile complete

    // ---------------- phase 5: GEMM2 k-loop, barrier-free ----------------
    f32x4 acc2[4][4];
    #pragma unroll
    for (int mf = 0; mf < 4; ++mf)
        #pragma unroll
        for (int nf = 0; nf < 4; ++nf)
            acc2[mf][nf] = f32x4{0.f, 0.f, 0.f, 0.f};

    {
        bf16x8 bc[4], bn[4];
        #pragma unroll
        for (int nf = 0; nf < 4; ++nf)
            bc[nf] = *(const bf16x8*)(w2p + nf * 512);
        #pragma unroll
        for (int kb = 0; kb < 8; ++kb) {
            if (kb < 7) {
                #pragma unroll
                for (int nf = 0; nf < 4; ++nf)
                    bn[nf] = *(const bf16x8*)(w2p + (size_t)(kb + 1) * 8192 + nf * 512);
            }
            bf16x8 a[4];
            #pragma unroll
            for (int mf = 0; mf < 4; ++mf)
                a[mf] = *(const bf16x8*)&ldsA[((kb * 4 + mf) * 64 + lane) * 8];
            #pragma unroll
            for (int mf = 0; mf < 4; ++mf)
                #pragma unroll
                for (int nf = 0; nf < 4; ++nf)
                    acc2[mf][nf] = __builtin_amdgcn_mfma_f32_16x16x32_bf16(
                        a[mf], bc[nf], acc2[mf][nf], 0, 0, 0);
            #pragma unroll
            for (int nf = 0; nf < 4; ++nf) bc[nf] = bn[nf];
        }
    }

    // epilogue: out = relu(acc2 + b2), f32; plus this block's tail section
    const int rbase = bm * 64 + lk * 4;
    const int cbase = w * 64 + l15;
    #pragma unroll
    for (int nf = 0; nf < 4; ++nf) {
        const int col = cbase + nf * 16;
        const float bv = b2[col];
        #pragma unroll
        for (int mf = 0; mf < 4; ++mf) {
            #pragma unroll
            for (int r = 0; r < 4; ++r) {
                float v = fmaxf(acc2[mf][nf][r] + bv, 0.f);
                out[(size_t)(rbase + mf * 16 + r) * HD + col] = v;
            }
        }
    }
    // tail: pos_skip passthrough (192 floats) + batch (64 floats) for our rows
    {
        const size_t o1 = (size_t)MTOT * HD;
        if (tid < 192) out[o1 + (size_t)bm * 192 + tid] = pos_skip[(size_t)bm * 192 + tid];
        if (tid < 64)  out[o1 + (size_t)MTOT * 3 + (size_t)bm * 64 + tid] = (float)cloud;
    }
}

extern "C" void kernel_launch(void* const* d_in, const int* in_sizes, int n_in,
                              void* d_out, int out_size, void* d_ws, size_t ws_size,
                              hipStream_t stream)
{
    const float* x        = (const float*)d_in[0];
    const float* pos      = (const float*)d_in[1];
    const float* x_skip   = (const float*)d_in[2];
    const float* pos_skip = (const float*)d_in[3];
    const float* W1       = (const float*)d_in[4];
    const float* b1       = (const float*)d_in[5];
    const float* W2       = (const float*)d_in[6];
    const float* b2       = (const float*)d_in[7];
    float* out = (float*)d_out;

    char* ws = (char*)d_ws;
    unsigned short* W1f  = (unsigned short*)(ws + W1F_OFF);
    unsigned short* W2f  = (unsigned short*)(ws + W2F_OFF);

    prep_kernel<<<PREP_B1 + PREP_B2, 256, 0, stream>>>(W1, W2, W1f, W2f);
    fp_fused_kernel<<<MTOT / 64, 256, 0, stream>>>(
        x, x_skip, pos, pos_skip, W1f, W2f, b1, b2, out);
}